// Round 1
// baseline (150.779 us; speedup 1.0000x reference)
//
#include <hip/hip_runtime.h>
#include <math.h>

#define Bn 32
#define Nn 2000
#define En 32000
#define Vn 100000
#define Dn 128
#define Rn 39
#define Kn 8

#define SUBS 8
#define NPS (Nn / SUBS)   // 250 nodes per sub-block
#define WPG 64            // gather waves per graph (each handles node PAIRS)
#define NPAIR (Nn / 2)    // 1000 node pairs per graph
#define EQ (En / 4)       // 8000 edge-quads per graph
#define NR (NPS * Rn)     // 9750 LDS cells per sub-block

// Workspace layout (no aliasing):
//   [ 0)          : inv     float[B*E]          =  4,096,000
//   [ 4,096,000)  : a       float[B*N*K]        =  2,048,000
//   [ 6,144,000)  : partial float[B*9*WPG*128]  =  9,437,184   ([b][k][W][d])
//   [15,581,184)  : gmat    float[B*9*128]      =    147,456
//   [15,728,640)  : counter int[B]              =        128
//
// R16 = R15 (proven 146.5us) + three boundary/latency cuts:
//   (1) K4+K5 fused: last matvec block per graph (device-scope atomic counter,
//       zeroed by K1 three kernels earlier) does sum+bias+L2-norm. One fewer
//       launch boundary + gmat drain.
//   (2) K1 converts LDS counts -> reciprocals ONCE (9750 rcp) instead of
//       ~16K predicated IEEE divides during the pass-2 edge scan.
//   (3) K3 preloads the 8KB node-id table into LDS: removes the dependent
//       global nid load from the gather chain (LDS broadcast instead).
// blockIdx.x = graph everywhere -> XCD affinity (R2 evidence: 9x fetch cut).

// K1: fused cnt+inv. 8 blocks/graph own dst-ranges. Fused mad-filter:
// y = dst*39+et - sub*9750; in-range iff (unsigned)y < 9750.
__global__ __launch_bounds__(1024) void cntinv_kernel(const int* __restrict__ edge_index,
                                                      const int* __restrict__ edge_type,
                                                      float* __restrict__ inv,
                                                      int* __restrict__ counter) {
    int b = blockIdx.x, sub = blockIdx.y;
    if (sub == 0 && threadIdx.x == 0) counter[b] = 0;   // arm K4's finish-election
    int base = sub * NR;
    __shared__ int loc[NR];                       // 39 KB
    for (int i = threadIdx.x; i < NR; i += 1024) loc[i] = 0;
    __syncthreads();
    const int4* dst4 = (const int4*)(edge_index + (b * 2 + 1) * En);
    const int4* et4  = (const int4*)(edge_type + b * En);
    for (int q = threadIdx.x; q < EQ; q += 1024) {
        int4 d = dst4[q]; int4 t = et4[q]; int y;
        y = d.x * Rn + t.x - base; if ((unsigned)y < NR) atomicAdd(&loc[y], 1);
        y = d.y * Rn + t.y - base; if ((unsigned)y < NR) atomicAdd(&loc[y], 1);
        y = d.z * Rn + t.z - base; if ((unsigned)y < NR) atomicAdd(&loc[y], 1);
        y = d.w * Rn + t.w - base; if ((unsigned)y < NR) atomicAdd(&loc[y], 1);
    }
    __syncthreads();
    // counts -> reciprocals in place (each thread owns cell i: read-then-write same slot).
    // count==0 cells become inf but are never referenced by pass 2 (any in-range
    // edge incremented its own cell in pass 1).
    float* finv = (float*)loc;
    for (int i = threadIdx.x; i < NR; i += 1024) {
        int c = loc[i];
        finv[i] = 1.0f / (float)c;
    }
    __syncthreads();
    float* ivb = inv + (size_t)b * En;
    for (int q = threadIdx.x; q < EQ; q += 1024) {
        int4 d = dst4[q]; int4 t = et4[q];
        int e = 4 * q, y;
        y = d.x * Rn + t.x - base; if ((unsigned)y < NR) ivb[e]     = finv[y];
        y = d.y * Rn + t.y - base; if ((unsigned)y < NR) ivb[e + 1] = finv[y];
        y = d.z * Rn + t.z - base; if ((unsigned)y < NR) ivb[e + 2] = finv[y];
        y = d.w * Rn + t.w - base; if ((unsigned)y < NR) ivb[e + 3] = finv[y];
    }
}

// K2: 8 blocks/graph own src-ranges. Streaming scan, fused mad-filter, ONE LDS
// atomic/edge into s[src*39+t] (stride 39, coprime to 32 banks), then
// a[n][k] = s @ comp.
__global__ __launch_bounds__(1024) void a_kernel(const int* __restrict__ edge_index,
                                                 const int* __restrict__ edge_type,
                                                 const float* __restrict__ inv,
                                                 const float* __restrict__ comp,
                                                 float* __restrict__ a) {
    int b = blockIdx.x, sub = blockIdx.y;
    int base = sub * NR;
    __shared__ float s[NR];                       // 39 KB
    __shared__ float comp_l[Rn * Kn];
    for (int i = threadIdx.x; i < NR; i += 1024) s[i] = 0.0f;
    if (threadIdx.x < Rn * Kn) comp_l[threadIdx.x] = comp[threadIdx.x];
    __syncthreads();
    const int4*   src4 = (const int4*)(edge_index + (b * 2 + 0) * En);
    const int4*   et4  = (const int4*)(edge_type + b * En);
    const float4* iv4  = (const float4*)(inv + (size_t)b * En);
    for (int q = threadIdx.x; q < EQ; q += 1024) {
        int4 sv = src4[q]; int4 tv = et4[q]; float4 iv = iv4[q]; int y;
        y = sv.x * Rn + tv.x - base; if ((unsigned)y < NR) atomicAdd(&s[y], iv.x);
        y = sv.y * Rn + tv.y - base; if ((unsigned)y < NR) atomicAdd(&s[y], iv.y);
        y = sv.z * Rn + tv.z - base; if ((unsigned)y < NR) atomicAdd(&s[y], iv.z);
        y = sv.w * Rn + tv.w - base; if ((unsigned)y < NR) atomicAdd(&s[y], iv.w);
    }
    __syncthreads();
    float* g = a + ((size_t)b * Nn + sub * NPS) * Kn;
    for (int i = threadIdx.x; i < NPS * Kn; i += 1024) {   // 2000 outputs
        int n = i >> 3, k = i & 7;
        float acc = 0.0f;
        const float* srow = &s[n * Rn];
        for (int t = 0; t < Rn; t++) acc += srow[t] * comp_l[t * Kn + k];
        g[i] = acc;
    }
}

// K3: paired gather. Wave W owns node pairs {p : p mod 64 == W}; lanes 0-31
// cover node 2p (d = 4*(lane&31)..+3 via float4), lanes 32-63 cover node 2p+1.
// Batch-8 pairs (8 KB in flight/wave). Node-id table staged in LDS so the
// embedding-row fetch chain starts from an LDS broadcast, not an L2 load.
// Half-wave accumulators merged by shfl(+32); lanes 0-31 store 512B-coalesced.
__global__ __launch_bounds__(256) void gather_kernel(const int* __restrict__ node_ids,
                                                     const float* __restrict__ emb,
                                                     const float* __restrict__ a,
                                                     float* __restrict__ partial) {
    int b = blockIdx.x;
    int lane = threadIdx.x & 63, wv = threadIdx.x >> 6;
    int W = blockIdx.y * 4 + wv;                  // wave id in [0, WPG)
    int half = lane >> 5;                         // 0: even node, 1: odd node
    int dl = lane & 31;                           // float4 slot: d = 4*dl..4*dl+3
    __shared__ int nid_l[Nn];                     // 8 KB, coalesced preload
    const int* nb = node_ids + b * Nn;
    for (int i = threadIdx.x; i < Nn; i += 256) nid_l[i] = nb[i];
    __syncthreads();
    float4 acc[9];
#pragma unroll
    for (int k = 0; k < 9; k++) acc[k] = make_float4(0.f, 0.f, 0.f, 0.f);
    const float* ab = a + (size_t)b * Nn * Kn;
    for (int p0 = W; p0 < NPAIR; p0 += 8 * WPG) { // 2 outer iters
        bool   has[8];
        int    node[8];
        float4 v[8];
        float4 a0[8], a1[8];
#pragma unroll
        for (int i = 0; i < 8; i++) {
            int p = p0 + i * WPG;
            has[i] = p < NPAIR;
            node[i] = (has[i] ? 2 * p : 0) + half;
        }
#pragma unroll
        for (int i = 0; i < 8; i++) {             // 8 batched 1KB row loads
            int nid = nid_l[node[i]];
            v[i] = has[i] ? ((const float4*)(emb + (size_t)nid * Dn))[dl]
                          : make_float4(0.f, 0.f, 0.f, 0.f);
            const float4* ar = (const float4*)(ab + (size_t)node[i] * Kn);
            a0[i] = ar[0]; a1[i] = ar[1];
        }
#pragma unroll
        for (int i = 0; i < 8; i++) {
            float w[9] = {a0[i].x, a0[i].y, a0[i].z, a0[i].w,
                          a1[i].x, a1[i].y, a1[i].z, a1[i].w, 1.0f};
#pragma unroll
            for (int k = 0; k < 9; k++) {
                acc[k].x += w[k] * v[i].x;
                acc[k].y += w[k] * v[i].y;
                acc[k].z += w[k] * v[i].z;
                acc[k].w += w[k] * v[i].w;
            }
        }
    }
    // merge odd-node half into even half (same d-range), store coalesced
#pragma unroll
    for (int k = 0; k < 9; k++) {
        acc[k].x += __shfl_down(acc[k].x, 32, 64);
        acc[k].y += __shfl_down(acc[k].y, 32, 64);
        acc[k].z += __shfl_down(acc[k].z, 32, 64);
        acc[k].w += __shfl_down(acc[k].w, 32, 64);
    }
    if (half == 0) {
#pragma unroll
        for (int k = 0; k < 9; k++) {
            float4* gp = (float4*)(partial + (((size_t)b * 9 + k) * WPG + W) * Dn);
            gp[dl] = acc[k];
        }
    }
}

// K4 (+fused K5): one block per (graph, matrix m). Reduce over W is a
// CONTIGUOUS 32 KB float4 stream ([m] slab of partial), then matvec -> gmat.
// The LAST block per graph (device-scope atomic counter, zeroed by K1) sums
// the 9 gmat rows, adds the bias term and L2-normalizes into out.
__global__ __launch_bounds__(256) void matvec_kernel(const float* __restrict__ partial,
                                                     const float* __restrict__ root,
                                                     const float* __restrict__ bases,
                                                     const float* __restrict__ bias,
                                                     float* __restrict__ gmat,
                                                     int* __restrict__ counter,
                                                     float* __restrict__ out) {
    int b = blockIdx.x, m = blockIdx.y;
    int tid = threadIdx.x;
    __shared__ float4 ts4[Dn / 4];                // ts[128] as 32 float4
    __shared__ float tsh[8][Dn];
    int dg = tid & 31, part = tid >> 5;           // 32 d-groups x 8 W-parts
    const float4* p4 = (const float4*)(partial + ((size_t)b * 9 + m) * WPG * Dn);
    float4 sum = make_float4(0.f, 0.f, 0.f, 0.f);
    for (int c = part; c < WPG; c += 8) {         // 8 iters, contiguous stream
        float4 v = p4[c * 32 + dg];
        sum.x += v.x; sum.y += v.y; sum.z += v.z; sum.w += v.w;
    }
    ((float4*)tsh[part])[dg] = sum;
    __syncthreads();
    if (part == 0) {
        float4 t = make_float4(0.f, 0.f, 0.f, 0.f);
#pragma unroll
        for (int r = 0; r < 8; r++) {
            float4 v = ((float4*)tsh[r])[dg];
            t.x += v.x; t.y += v.y; t.z += v.z; t.w += v.w;
        }
        ts4[dg] = t;
    }
    __syncthreads();
    const float* ts = (const float*)ts4;
    const float* M  = (m == 8) ? root : bases + (size_t)m * Dn * Dn;
    int d = tid & (Dn - 1), h = tid >> 7;
    float g = 0.0f;
#pragma unroll 8
    for (int j = h * 64; j < h * 64 + 64; j++) g += ts[j] * M[j * Dn + d];
    __syncthreads();
    tsh[h][d] = g;
    __syncthreads();
    if (h == 0) gmat[((size_t)b * 9 + m) * Dn + d] = tsh[0][d] + tsh[1][d];

    // ---- fused finish (former K5): elect last block of graph b ----
    __syncthreads();                              // all gmat stores issued
    __shared__ int lastFlag;
    if (tid == 0) {
        __threadfence();                          // publish this block's row
        lastFlag = (atomicAdd(&counter[b], 1) == 8);
    }
    __syncthreads();
    if (!lastFlag) return;
    __threadfence();                              // acquire other blocks' rows
    __shared__ float s2[2];
    float gf = 0.0f;
    int dd = tid & (Dn - 1);
    if (tid < Dn) {
        gf = (float)Nn * bias[dd];
        const float* gb = gmat + (size_t)b * 9 * Dn + dd;
#pragma unroll
        for (int mm = 0; mm < 9; mm++) gf += gb[mm * Dn];
        float ss = gf * gf;
#pragma unroll
        for (int off = 32; off > 0; off >>= 1) ss += __shfl_down(ss, off, 64);
        if ((tid & 63) == 0) s2[tid >> 6] = ss;
    }
    __syncthreads();
    if (tid < Dn) {
        float nrm = sqrtf(s2[0] + s2[1]);
        out[b * Dn + dd] = gf / fmaxf(nrm, 1e-5f);
    }
}

extern "C" void kernel_launch(void* const* d_in, const int* in_sizes, int n_in,
                              void* d_out, int out_size, void* d_ws, size_t ws_size,
                              hipStream_t stream) {
    const int*   node_ids   = (const int*)d_in[0];
    const int*   edge_index = (const int*)d_in[1];
    const int*   edge_type  = (const int*)d_in[2];
    const float* embedding  = (const float*)d_in[3];
    const float* bases      = (const float*)d_in[4];
    const float* comp       = (const float*)d_in[5];
    const float* root       = (const float*)d_in[6];
    const float* bias       = (const float*)d_in[7];
    float*       out        = (float*)d_out;

    char* w = (char*)d_ws;
    float* inv     = (float*)(w + 0);
    float* a       = (float*)(w + 4096000);
    float* partial = (float*)(w + 6144000);
    float* gmat    = (float*)(w + 15581184);
    int*   counter = (int*)  (w + 15728640);

    cntinv_kernel<<<dim3(Bn, SUBS),    1024, 0, stream>>>(edge_index, edge_type, inv, counter);
    a_kernel     <<<dim3(Bn, SUBS),    1024, 0, stream>>>(edge_index, edge_type, inv, comp, a);
    gather_kernel<<<dim3(Bn, WPG / 4), 256,  0, stream>>>(node_ids, embedding, a, partial);
    matvec_kernel<<<dim3(Bn, 9),       256,  0, stream>>>(partial, root, bases, bias, gmat, counter, out);
}

// Round 2
// 140.679 us; speedup vs baseline: 1.0718x; 1.0718x over previous
//
#include <hip/hip_runtime.h>
#include <math.h>

#define Bn 32
#define Nn 2000
#define En 32000
#define Vn 100000
#define Dn 128
#define Rn 39
#define Kn 8

#define SUBS 8
#define NPS (Nn / SUBS)   // 250 nodes per sub-block
#define NPAIR (Nn / 2)    // 1000 node pairs per graph
#define EQ (En / 4)       // 8000 edge-quads per graph
#define NR (NPS * Rn)     // 9750 LDS cells per sub-block
#define GBLK 16           // gather blocks per graph
#define WSLOT (GBLK * 8)  // 128 wave-slots per graph (8 waves/block)

// Workspace layout (no aliasing):
//   [ 0)          : inv     float[B*E]           =  4,096,000
//   [ 4,096,000)  : a       float[B*N*K]         =  2,048,000
//   [ 6,144,000)  : partial float[B*9*GBLK*128]  =  2,359,296   ([b][k][blk][d])
//   [ 8,503,296)  : gmat    float[B*9*128]       =    147,456
//
// R17 = R15 (proven 146.5us) + K1 rcp (safe R16 piece) + gather restructure:
//   - K3: 512-thread blocks (8 waves), ONE batch-4x2 pass per wave, cross-wave
//     LDS reduction 8->1. partial shrinks 9.4MB -> 2.36MB (R14->R15 evidence:
//     partial round-trip converts to wall time at ~HBM rate), and gather
//     occupancy doubles (16 waves/CU) for latency hiding.
//   - K4: reduce stream is 8KB/block (16 rows) instead of 32KB.
//   - R16's election fusion + fences REVERTED (measured +4.3us).
// blockIdx.x = graph everywhere -> XCD affinity (R2 evidence: 9x fetch cut).

// K1: fused cnt+inv. 8 blocks/graph own dst-ranges. Fused mad-filter:
// y = dst*39+et - sub*9750; in-range iff (unsigned)y < 9750.
// Counts converted to reciprocals ONCE in LDS (9750 rcp) so pass 2 is a
// pure lookup (no per-edge divide).
__global__ __launch_bounds__(1024) void cntinv_kernel(const int* __restrict__ edge_index,
                                                      const int* __restrict__ edge_type,
                                                      float* __restrict__ inv) {
    int b = blockIdx.x, sub = blockIdx.y;
    int base = sub * NR;
    __shared__ int loc[NR];                       // 39 KB
    for (int i = threadIdx.x; i < NR; i += 1024) loc[i] = 0;
    __syncthreads();
    const int4* dst4 = (const int4*)(edge_index + (b * 2 + 1) * En);
    const int4* et4  = (const int4*)(edge_type + b * En);
    for (int q = threadIdx.x; q < EQ; q += 1024) {
        int4 d = dst4[q]; int4 t = et4[q]; int y;
        y = d.x * Rn + t.x - base; if ((unsigned)y < NR) atomicAdd(&loc[y], 1);
        y = d.y * Rn + t.y - base; if ((unsigned)y < NR) atomicAdd(&loc[y], 1);
        y = d.z * Rn + t.z - base; if ((unsigned)y < NR) atomicAdd(&loc[y], 1);
        y = d.w * Rn + t.w - base; if ((unsigned)y < NR) atomicAdd(&loc[y], 1);
    }
    __syncthreads();
    // counts -> reciprocals in place (each thread owns cell i). count==0 cells
    // become inf but are never referenced by pass 2.
    float* finv = (float*)loc;
    for (int i = threadIdx.x; i < NR; i += 1024) {
        int c = loc[i];
        finv[i] = 1.0f / (float)c;
    }
    __syncthreads();
    float* ivb = inv + (size_t)b * En;
    for (int q = threadIdx.x; q < EQ; q += 1024) {
        int4 d = dst4[q]; int4 t = et4[q];
        int e = 4 * q, y;
        y = d.x * Rn + t.x - base; if ((unsigned)y < NR) ivb[e]     = finv[y];
        y = d.y * Rn + t.y - base; if ((unsigned)y < NR) ivb[e + 1] = finv[y];
        y = d.z * Rn + t.z - base; if ((unsigned)y < NR) ivb[e + 2] = finv[y];
        y = d.w * Rn + t.w - base; if ((unsigned)y < NR) ivb[e + 3] = finv[y];
    }
}

// K2: 8 blocks/graph own src-ranges. Streaming scan, fused mad-filter, ONE LDS
// atomic/edge into s[src*39+t] (stride 39, coprime to 32 banks), then
// a[n][k] = s @ comp.
__global__ __launch_bounds__(1024) void a_kernel(const int* __restrict__ edge_index,
                                                 const int* __restrict__ edge_type,
                                                 const float* __restrict__ inv,
                                                 const float* __restrict__ comp,
                                                 float* __restrict__ a) {
    int b = blockIdx.x, sub = blockIdx.y;
    int base = sub * NR;
    __shared__ float s[NR];                       // 39 KB
    __shared__ float comp_l[Rn * Kn];
    for (int i = threadIdx.x; i < NR; i += 1024) s[i] = 0.0f;
    if (threadIdx.x < Rn * Kn) comp_l[threadIdx.x] = comp[threadIdx.x];
    __syncthreads();
    const int4*   src4 = (const int4*)(edge_index + (b * 2 + 0) * En);
    const int4*   et4  = (const int4*)(edge_type + b * En);
    const float4* iv4  = (const float4*)(inv + (size_t)b * En);
    for (int q = threadIdx.x; q < EQ; q += 1024) {
        int4 sv = src4[q]; int4 tv = et4[q]; float4 iv = iv4[q]; int y;
        y = sv.x * Rn + tv.x - base; if ((unsigned)y < NR) atomicAdd(&s[y], iv.x);
        y = sv.y * Rn + tv.y - base; if ((unsigned)y < NR) atomicAdd(&s[y], iv.y);
        y = sv.z * Rn + tv.z - base; if ((unsigned)y < NR) atomicAdd(&s[y], iv.z);
        y = sv.w * Rn + tv.w - base; if ((unsigned)y < NR) atomicAdd(&s[y], iv.w);
    }
    __syncthreads();
    float* g = a + ((size_t)b * Nn + sub * NPS) * Kn;
    for (int i = threadIdx.x; i < NPS * Kn; i += 1024) {   // 2000 outputs
        int n = i >> 3, k = i & 7;
        float acc = 0.0f;
        const float* srow = &s[n * Rn];
        for (int t = 0; t < Rn; t++) acc += srow[t] * comp_l[t * Kn + k];
        g[i] = acc;
    }
}

// K3: paired gather, 8 waves/block, 16 blocks/graph. Wave-slot Wl in [0,128)
// owns pairs {p : p mod 128 == Wl} -> 8 pairs, processed in two batch-4
// rounds. Lanes 0-31 cover node 2p (d = 4*(lane&31)..+3 via float4), lanes
// 32-63 cover node 2p+1; halves merged by shfl(+32). Then the 8 waves reduce
// 8->1 through LDS and the block stores ONE 9x128 slab -> partial is 4x
// smaller than R15 (2.36 MB total).
__global__ __launch_bounds__(512, 4) void gather_kernel(const int* __restrict__ node_ids,
                                                        const float* __restrict__ emb,
                                                        const float* __restrict__ a,
                                                        float* __restrict__ partial) {
    int b = blockIdx.x;
    int lane = threadIdx.x & 63, wv = threadIdx.x >> 6;
    int Wl = blockIdx.y * 8 + wv;                 // wave-slot in [0, WSLOT)
    int half = lane >> 5;                         // 0: even node, 1: odd node
    int dl = lane & 31;                           // float4 slot: d = 4*dl..4*dl+3
    __shared__ float red[8][9][Dn];               // 36.9 KB
    float4 acc[9];
#pragma unroll
    for (int k = 0; k < 9; k++) acc[k] = make_float4(0.f, 0.f, 0.f, 0.f);
    const int*   nb = node_ids + b * Nn;
    const float* ab = a + (size_t)b * Nn * Kn;
#pragma unroll
    for (int i0 = 0; i0 < 8; i0 += 4) {           // two batch-4 rounds
        bool   has[4];
        int    node[4];
        float4 v[4];
        float4 a0[4], a1[4];
#pragma unroll
        for (int i = 0; i < 4; i++) {
            int p = Wl + (i0 + i) * WSLOT;
            has[i] = p < NPAIR;
            node[i] = (has[i] ? 2 * p : 0) + half;
        }
#pragma unroll
        for (int i = 0; i < 4; i++) {             // 4 batched 1KB row loads
            int nid = nb[node[i]];
            v[i] = has[i] ? ((const float4*)(emb + (size_t)nid * Dn))[dl]
                          : make_float4(0.f, 0.f, 0.f, 0.f);
            const float4* ar = (const float4*)(ab + (size_t)node[i] * Kn);
            a0[i] = ar[0]; a1[i] = ar[1];
        }
#pragma unroll
        for (int i = 0; i < 4; i++) {
            float w[9] = {a0[i].x, a0[i].y, a0[i].z, a0[i].w,
                          a1[i].x, a1[i].y, a1[i].z, a1[i].w, 1.0f};
#pragma unroll
            for (int k = 0; k < 9; k++) {
                acc[k].x += w[k] * v[i].x;
                acc[k].y += w[k] * v[i].y;
                acc[k].z += w[k] * v[i].z;
                acc[k].w += w[k] * v[i].w;
            }
        }
    }
    // merge odd-node half into even half (same d-range)
#pragma unroll
    for (int k = 0; k < 9; k++) {
        acc[k].x += __shfl_down(acc[k].x, 32, 64);
        acc[k].y += __shfl_down(acc[k].y, 32, 64);
        acc[k].z += __shfl_down(acc[k].z, 32, 64);
        acc[k].w += __shfl_down(acc[k].w, 32, 64);
    }
    if (half == 0) {
#pragma unroll
        for (int k = 0; k < 9; k++)
            ((float4*)red[wv][k])[dl] = acc[k];
    }
    __syncthreads();
    // cross-wave reduce 8->1: threads 0..287 each own one (k, d4) float4 slot
    int slot = threadIdx.x;
    if (slot < 9 * (Dn / 4)) {
        int k = slot >> 5, d4 = slot & 31;
        float4 t = make_float4(0.f, 0.f, 0.f, 0.f);
#pragma unroll
        for (int w = 0; w < 8; w++) {
            float4 v = ((const float4*)red[w][k])[d4];
            t.x += v.x; t.y += v.y; t.z += v.z; t.w += v.w;
        }
        float4* gp = (float4*)(partial + (((size_t)b * 9 + k) * GBLK + blockIdx.y) * Dn);
        gp[d4] = t;
    }
}

// K4: one block per (graph, matrix m). Reduce over 16 block-slabs is a
// CONTIGUOUS 8 KB float4 stream ([m] slab of partial). Then matvec -> gmat.
__global__ __launch_bounds__(256) void matvec_kernel(const float* __restrict__ partial,
                                                     const float* __restrict__ root,
                                                     const float* __restrict__ bases,
                                                     float* __restrict__ gmat) {
    int b = blockIdx.x, m = blockIdx.y;
    int tid = threadIdx.x;
    __shared__ float4 ts4[Dn / 4];                // ts[128] as 32 float4
    __shared__ float tsh[8][Dn];
    int dg = tid & 31, part = tid >> 5;           // 32 d-groups x 8 parts
    const float4* p4 = (const float4*)(partial + ((size_t)b * 9 + m) * GBLK * Dn);
    float4 sum = make_float4(0.f, 0.f, 0.f, 0.f);
    for (int c = part; c < GBLK; c += 8) {        // 2 iters, contiguous stream
        float4 v = p4[c * 32 + dg];
        sum.x += v.x; sum.y += v.y; sum.z += v.z; sum.w += v.w;
    }
    ((float4*)tsh[part])[dg] = sum;
    __syncthreads();
    if (part == 0) {
        float4 t = make_float4(0.f, 0.f, 0.f, 0.f);
#pragma unroll
        for (int r = 0; r < 8; r++) {
            float4 v = ((float4*)tsh[r])[dg];
            t.x += v.x; t.y += v.y; t.z += v.z; t.w += v.w;
        }
        ts4[dg] = t;
    }
    __syncthreads();
    const float* ts = (const float*)ts4;
    const float* M  = (m == 8) ? root : bases + (size_t)m * Dn * Dn;
    int d = tid & (Dn - 1), h = tid >> 7;
    float g = 0.0f;
#pragma unroll 8
    for (int j = h * 64; j < h * 64 + 64; j++) g += ts[j] * M[j * Dn + d];
    __syncthreads();
    tsh[h][d] = g;
    __syncthreads();
    if (h == 0) gmat[((size_t)b * 9 + m) * Dn + d] = tsh[0][d] + tsh[1][d];
}

// K5: sum the 9 matvec outputs, add bias term, L2-normalize.
__global__ __launch_bounds__(128) void norm_kernel(const float* __restrict__ gmat,
                                                   const float* __restrict__ bias,
                                                   float* __restrict__ out) {
    int b = blockIdx.x, d = threadIdx.x;
    float g = (float)Nn * bias[d];
    const float* gb = gmat + (size_t)b * 9 * Dn + d;
#pragma unroll
    for (int m = 0; m < 9; m++) g += gb[m * Dn];
    float ss = g * g;
#pragma unroll
    for (int off = 32; off > 0; off >>= 1) ss += __shfl_down(ss, off, 64);
    __shared__ float s2[2];
    if ((threadIdx.x & 63) == 0) s2[threadIdx.x >> 6] = ss;
    __syncthreads();
    float nrm = sqrtf(s2[0] + s2[1]);
    out[b * Dn + d] = g / fmaxf(nrm, 1e-5f);
}

extern "C" void kernel_launch(void* const* d_in, const int* in_sizes, int n_in,
                              void* d_out, int out_size, void* d_ws, size_t ws_size,
                              hipStream_t stream) {
    const int*   node_ids   = (const int*)d_in[0];
    const int*   edge_index = (const int*)d_in[1];
    const int*   edge_type  = (const int*)d_in[2];
    const float* embedding  = (const float*)d_in[3];
    const float* bases      = (const float*)d_in[4];
    const float* comp       = (const float*)d_in[5];
    const float* root       = (const float*)d_in[6];
    const float* bias       = (const float*)d_in[7];
    float*       out        = (float*)d_out;

    char* w = (char*)d_ws;
    float* inv     = (float*)(w + 0);
    float* a       = (float*)(w + 4096000);
    float* partial = (float*)(w + 6144000);
    float* gmat    = (float*)(w + 8503296);

    cntinv_kernel<<<dim3(Bn, SUBS), 1024, 0, stream>>>(edge_index, edge_type, inv);
    a_kernel     <<<dim3(Bn, SUBS), 1024, 0, stream>>>(edge_index, edge_type, inv, comp, a);
    gather_kernel<<<dim3(Bn, GBLK), 512,  0, stream>>>(node_ids, embedding, a, partial);
    matvec_kernel<<<dim3(Bn, 9),    256,  0, stream>>>(partial, root, bases, gmat);
    norm_kernel  <<<Bn, 128, 0, stream>>>(gmat, bias, out);
}